// Round 5
// baseline (223.522 us; speedup 1.0000x reference)
//
#include <hip/hip_runtime.h>
#include <stdint.h>

#define DMODEL 1024
#define NHEADS 16
#define DKH 64
#define BATCH 2
#define SEQ 2048
#define MTOT (BATCH*SEQ)   // 4096

typedef __bf16 bf16x8 __attribute__((ext_vector_type(8)));
typedef __bf16 bf16x4 __attribute__((ext_vector_type(4)));
typedef float  f32x4  __attribute__((ext_vector_type(4)));

__device__ __forceinline__ f32x4 mfma16(bf16x8 a, bf16x8 b, f32x4 c){
  return __builtin_amdgcn_mfma_f32_16x16x32_bf16(a, b, c, 0, 0, 0);
}

// async global->LDS, 16B per lane. LDS dest wave-uniform base; lane i lands at base + i*16.
__device__ __forceinline__ void gload_lds16(const void* g, void* l){
  __builtin_amdgcn_global_load_lds(
      (const __attribute__((address_space(1))) uint32_t*)(uintptr_t)g,
      (__attribute__((address_space(3))) uint32_t*)(uint32_t)(uintptr_t)l,
      16, 0, 0);
}

__device__ __forceinline__ unsigned short f2bf(float f){
  unsigned u = __builtin_bit_cast(unsigned, f);
  u += 0x7fff + ((u >> 16) & 1);          // round-to-nearest-even
  return (unsigned short)(u >> 16);
}

// ---------------- fp32 -> bf16 convert ----------------
__global__ void cvt_kernel(const float* __restrict__ in, unsigned short* __restrict__ out, int n4){
  const float4*  in4  = (const float4*)in;
  ushort4*       out4 = (ushort4*)out;
  int i = blockIdx.x * blockDim.x + threadIdx.x;
  int stride = gridDim.x * blockDim.x;
  for (; i < n4; i += stride){
    float4 v = in4[i];
    ushort4 o;
    o.x = f2bf(v.x); o.y = f2bf(v.y); o.z = f2bf(v.z); o.w = f2bf(v.w);
    out4[i] = o;
  }
}

// ---------------- GEMM: C[m,n] = sum_k A[m,k]*B[n,k]  (B^T layout) ----------------
template<int EPI>
__global__ __launch_bounds__(256)
void gemm_bt(const __bf16* __restrict__ Ag, const __bf16* __restrict__ Bg,
             int M, int N, int K,
             __bf16* __restrict__ Qo, __bf16* __restrict__ Ko, __bf16* __restrict__ Vt,
             float* __restrict__ Co){
  __shared__ __align__(16) __bf16 As[128*32];
  __shared__ __align__(16) __bf16 Bs[128*32];
  const int tid  = threadIdx.x;
  const int wave = tid >> 6, lane = tid & 63;
  const int wr = wave >> 1, wc = wave & 1;
  const int lr = lane & 15, lg = lane >> 4;
  const int m0 = blockIdx.y * 128, n0 = blockIdx.x * 128;

  f32x4 acc[4][4] = {};

  const int srow = lane >> 2;        // 0..15
  const int scol = (lane & 3) * 8;   // 0,8,16,24
  const __bf16* gA = Ag + (size_t)(m0 + wave*32 + srow) * K + scol;
  const __bf16* gB = Bg + (size_t)(n0 + wave*32 + srow) * K + scol;
  __bf16* lA = &As[(wave*32) * 32];
  __bf16* lB = &Bs[(wave*32) * 32];

  for (int k0 = 0; k0 < K; k0 += 32){
    __syncthreads();
    gload_lds16(gA + k0,                lA);
    gload_lds16(gA + k0 + (size_t)16*K, lA + 16*32);
    gload_lds16(gB + k0,                lB);
    gload_lds16(gB + k0 + (size_t)16*K, lB + 16*32);
    __syncthreads();

    bf16x8 af[4], bfv[4];
#pragma unroll
    for (int i = 0; i < 4; i++)
      af[i] = *(const bf16x8*)&As[(wr*64 + i*16 + lr)*32 + lg*8];
#pragma unroll
    for (int j = 0; j < 4; j++)
      bfv[j] = *(const bf16x8*)&Bs[(wc*64 + j*16 + lr)*32 + lg*8];
#pragma unroll
    for (int i = 0; i < 4; i++)
#pragma unroll
      for (int j = 0; j < 4; j++)
        acc[i][j] = mfma16(af[i], bfv[j], acc[i][j]);
  }

  if (EPI == 0){
    const int three = n0 >> 10;
#pragma unroll
    for (int i = 0; i < 4; i++){
#pragma unroll
      for (int j = 0; j < 4; j++){
#pragma unroll
        for (int r = 0; r < 4; r++){
          int m = m0 + wr*64 + i*16 + lg*4 + r;
          int n = n0 + wc*64 + j*16 + lr;
          int b = m >> 11, s = m & 2047;
          int h = (n >> 6) & 15, dk = n & 63;
          __bf16 val = (__bf16)acc[i][j][r];
          if (three == 0)      Qo[(((size_t)(b*NHEADS + h))*SEQ + s)*DKH + dk] = val;
          else if (three == 1) Ko[(((size_t)(b*NHEADS + h))*SEQ + s)*DKH + dk] = val;
          else                 Vt[(((size_t)(b*NHEADS + h))*DKH + dk)*SEQ + s] = val;
        }
      }
    }
  } else {
#pragma unroll
    for (int i = 0; i < 4; i++)
#pragma unroll
      for (int j = 0; j < 4; j++)
#pragma unroll
        for (int r = 0; r < 4; r++){
          int m = m0 + wr*64 + i*16 + lg*4 + r;
          int n = n0 + wc*64 + j*16 + lr;
          Co[(size_t)m * N + n] = acc[i][j][r];
        }
  }
}

// ---------------- causal flash attention, LDS-staged K/V, 2-wave blocks ----------------
// Q,K: [b,h,s,dk] bf16; Vt: [b,h,dk,s] bf16; Aout: [b,s,h*64+dk] bf16
// 64 q-tiles of 32 rows; block j handles pair (j, 63-j) -> constant 33 kv-rounds.
// Grid 32x32 = 1024 blocks = 4 blocks/CU (4 x 32KB LDS = 128KB): 4 independent
// barrier groups per CU so one block's staging drain overlaps others' compute.
// Per kv-round: K-tile [64][128B] + V-tile [64 dk][128B] staged via global_load_lds,
// XOR-swizzled (byte ^= (row&7)<<4; pre-swizzled global source + swizzled read).
__global__ __launch_bounds__(128)
void attn_kernel(const __bf16* __restrict__ Q, const __bf16* __restrict__ K,
                 const __bf16* __restrict__ Vt, __bf16* __restrict__ Aout){
  const int j  = blockIdx.x;                 // pair index 0..31
  const int bh = blockIdx.y;
  const int wave = threadIdx.x >> 6, lane = threadIdx.x & 63;
  const int lr = lane & 15, lg = lane >> 4;
  const int swz = (lr & 7) << 4;             // read-side XOR (row&7 == lr&7 for rows t*16+lr)

  const __bf16* Qh = Q + (size_t)bh*SEQ*DKH;
  const char* Kc = (const char*)(K  + (size_t)bh*SEQ*DKH);   // row stride 128B
  const char* Vc = (const char*)(Vt + (size_t)bh*DKH*SEQ);   // row stride 4096B

  __shared__ __align__(16) char lds[2][16384];   // [buf][ K 8KB | V 8KB ]

  // staging: wave stages rows [wave*32, wave*32+32) in 4 chunks of 8 rows;
  // lane covers (row8 = lane>>3, 16B chunk (lane&7)*16); global col pre-swizzled.
  const int row8 = lane >> 3;
  const int cG   = ((lane & 7) << 4) ^ (row8 << 4);

  const int b = bh >> 4, h = bh & 15;
  const float k2 = 0.125f * 1.44269504088896340736f;   // scale * log2(e)

  for (int ph = 0; ph < 2; ph++){
    const int tb  = ph ? (63 - j) : j;       // 32-row q-tile index
    const int qw  = tb*32 + wave*16;         // wave's first q row
    const int nkv = (tb >> 1) + 1;           // kv tiles of 64 covering tile rows

    bf16x8 qf0 = *(const bf16x8*)(Qh + (size_t)(qw + lr)*DKH + lg*8);
    bf16x8 qf1 = *(const bf16x8*)(Qh + (size_t)(qw + lr)*DKH + 32 + lg*8);

    f32x4 o[4] = {};
    float mrun = -1e30f, lrun = 0.f;

    // prologue: stage tile 0 into buf 0 (4 K chunks + 4 V chunks per wave)
#pragma unroll
    for (int i = 0; i < 4; i++){
      const int srow = wave*32 + i*8 + row8;
      gload_lds16(Kc + (size_t)srow*128 + cG,  &lds[0][wave*4096 + i*1024]);
      gload_lds16(Vc + (size_t)srow*4096 + cG, &lds[0][8192 + wave*4096 + i*1024]);
    }
    __syncthreads();

    for (int kb = 0; kb < nkv; kb++){
      const int kv0 = kb*64;
      if (kb + 1 < nkv){                     // stage next tile into other buffer
        const int nv0 = kv0 + 64;
#pragma unroll
        for (int i = 0; i < 4; i++){
          const int srow = wave*32 + i*8 + row8;
          gload_lds16(Kc + (size_t)(nv0 + srow)*128 + cG,
                      &lds[(kb+1)&1][wave*4096 + i*1024]);
          gload_lds16(Vc + (size_t)srow*4096 + (size_t)nv0*2 + cG,
                      &lds[(kb+1)&1][8192 + wave*4096 + i*1024]);
        }
      }
      const char* Ks = lds[kb&1];
      const char* Vs = lds[kb&1] + 8192;

      // ---- QK^T (swapped): sf[t][r] = S[kv0+t*16+lg*4+r][qw+lr]
      f32x4 sf[4];
      __builtin_amdgcn_s_setprio(1);
#pragma unroll
      for (int t = 0; t < 4; t++){
        const int row = t*16 + lr;
        bf16x8 kf0 = *(const bf16x8*)(Ks + row*128 + ((lg*16) ^ swz));
        bf16x8 kf1 = *(const bf16x8*)(Ks + row*128 + ((64 + lg*16) ^ swz));
        f32x4 c = {};
        c = mfma16(kf0, qf0, c);
        c = mfma16(kf1, qf1, c);
        sf[t] = c;
      }
      __builtin_amdgcn_s_setprio(0);
      // ---- mask + scale
      if (kv0 + 63 > qw){                    // tile touches the diagonal
        const int q = qw + lr;
#pragma unroll
        for (int t = 0; t < 4; t++)
#pragma unroll
          for (int r = 0; r < 4; r++){
            int kv = kv0 + t*16 + lg*4 + r;
            sf[t][r] = (kv <= q) ? sf[t][r]*k2 : -1e30f;
          }
      } else {
#pragma unroll
        for (int t = 0; t < 4; t++)
#pragma unroll
          for (int r = 0; r < 4; r++)
            sf[t][r] *= k2;
      }
      // ---- row max: in-lane 16 values, then across 4 lanes sharing q-row lr
      float mx = sf[0][0];
#pragma unroll
      for (int t = 0; t < 4; t++)
#pragma unroll
        for (int r = 0; r < 4; r++) mx = fmaxf(mx, sf[t][r]);
      mx = fmaxf(mx, __shfl_xor(mx, 16));
      mx = fmaxf(mx, __shfl_xor(mx, 32));

      float mn = fmaxf(mrun, mx);
      float alpha = __builtin_amdgcn_exp2f(mrun - mn);
      mrun = mn;
      lrun *= alpha;

      // ---- P = exp2(s-m), per-lane partial row sum
      float p[16];
#pragma unroll
      for (int t = 0; t < 4; t++)
#pragma unroll
        for (int r = 0; r < 4; r++){
          float v = __builtin_amdgcn_exp2f(sf[t][r] - mn);
          p[t*4 + r] = v;
          lrun += v;
        }

      // ---- rescale O (alpha of q-row lg*4+r lives at lane lg*4+r)
      float av[4];
#pragma unroll
      for (int r = 0; r < 4; r++) av[r] = __shfl(alpha, lg*4 + r);
#pragma unroll
      for (int n = 0; n < 4; n++)
#pragma unroll
        for (int r = 0; r < 4; r++) o[n][r] *= av[r];

      // ---- PV: pa regs ARE the A-fragment under relabeled k-slots
      bf16x8 pa0, pa1;
#pragma unroll
      for (int i = 0; i < 8; i++){ pa0[i] = (__bf16)p[i]; pa1[i] = (__bf16)p[8 + i]; }
      __builtin_amdgcn_s_setprio(1);
#pragma unroll
      for (int n = 0; n < 4; n++){
        const int row = n*16 + lr;
        bf16x4 vlo0 = *(const bf16x4*)(Vs + row*128 + ((lg*8) ^ swz));
        bf16x4 vhi0 = *(const bf16x4*)(Vs + row*128 + ((32 + lg*8) ^ swz));
        bf16x4 vlo1 = *(const bf16x4*)(Vs + row*128 + ((64 + lg*8) ^ swz));
        bf16x4 vhi1 = *(const bf16x4*)(Vs + row*128 + ((96 + lg*8) ^ swz));
        bf16x8 vf0 = __builtin_shufflevector(vlo0, vhi0, 0,1,2,3,4,5,6,7);
        bf16x8 vf1 = __builtin_shufflevector(vlo1, vhi1, 0,1,2,3,4,5,6,7);
        o[n] = mfma16(pa0, vf0, o[n]);
        o[n] = mfma16(pa1, vf1, o[n]);
      }
      __builtin_amdgcn_s_setprio(0);
      __syncthreads();                       // tile consumed; next staging safe
    }

    // ---- epilogue: full row sums, direct store (wave owns its 16 q-rows)
    lrun += __shfl_xor(lrun, 16);
    lrun += __shfl_xor(lrun, 32);
    float inv = 1.0f / lrun;
#pragma unroll
    for (int r = 0; r < 4; r++){
      float invr = __shfl(inv, lg*4 + r);
      __bf16* dst = Aout + ((size_t)b*SEQ + qw + lg*4 + r)*DMODEL + h*DKH;
#pragma unroll
      for (int n = 0; n < 4; n++)
        dst[n*16 + lr] = (__bf16)(o[n][r] * invr);
    }
  }
}

// ---------------- launch ----------------
extern "C" void kernel_launch(void* const* d_in, const int* in_sizes, int n_in,
                              void* d_out, int out_size, void* d_ws, size_t ws_size,
                              hipStream_t stream){
  const float* x    = (const float*)d_in[0];
  const float* wqkv = (const float*)d_in[1];
  const float* wout = (const float*)d_in[2];
  float* out = (float*)d_out;
  char* ws = (char*)d_ws;

  __bf16* xb  = (__bf16*)(ws);                    //  8,388,608  x bf16 [4096,1024]
  __bf16* Ab  = (__bf16*)(ws);                    //  attn out bf16 (alias, x dead)
  __bf16* wqb = (__bf16*)(ws + 8388608);          //  6,291,456  W_qkv bf16
  __bf16* wob = (__bf16*)(ws + 14680064);         //  2,097,152  W_out bf16
  __bf16* Qb  = (__bf16*)(ws + 16777216);         //  8,388,608  Q [b,h,s,dk]
  __bf16* Kb  = (__bf16*)(ws + 25165824);         //  8,388,608  K [b,h,s,dk]
  __bf16* Vtb = (__bf16*)(ws + 33554432);         //  8,388,608  V^T [b,h,dk,s]

  cvt_kernel<<<1024, 256, 0, stream>>>(x,    (unsigned short*)xb,  (MTOT*DMODEL)/4);
  cvt_kernel<<<1024, 256, 0, stream>>>(wqkv, (unsigned short*)wqb, (3*DMODEL*DMODEL)/4);
  cvt_kernel<<<256,  256, 0, stream>>>(wout, (unsigned short*)wob, (DMODEL*DMODEL)/4);

  gemm_bt<0><<<dim3(24, 32), 256, 0, stream>>>(xb, wqb, MTOT, 3*DMODEL, DMODEL,
                                               Qb, Kb, Vtb, nullptr);
  attn_kernel<<<dim3(32, 32), 128, 0, stream>>>(Qb, Kb, Vtb, Ab);
  gemm_bt<1><<<dim3(8, 32), 256, 0, stream>>>(Ab, wob, MTOT, DMODEL, DMODEL,
                                              nullptr, nullptr, nullptr, out);
}

// Round 6
// 203.480 us; speedup vs baseline: 1.0985x; 1.0985x over previous
//
#include <hip/hip_runtime.h>
#include <stdint.h>

#define DMODEL 1024
#define NHEADS 16
#define DKH 64
#define BATCH 2
#define SEQ 2048
#define MTOT (BATCH*SEQ)   // 4096

typedef __bf16 bf16x8 __attribute__((ext_vector_type(8)));
typedef __bf16 bf16x4 __attribute__((ext_vector_type(4)));
typedef float  f32x4  __attribute__((ext_vector_type(4)));

__device__ __forceinline__ f32x4 mfma16(bf16x8 a, bf16x8 b, f32x4 c){
  return __builtin_amdgcn_mfma_f32_16x16x32_bf16(a, b, c, 0, 0, 0);
}

// async global->LDS, 16B per lane. LDS dest wave-uniform base; lane i lands at base + i*16.
__device__ __forceinline__ void gload_lds16(const void* g, void* l){
  __builtin_amdgcn_global_load_lds(
      (const __attribute__((address_space(1))) uint32_t*)(uintptr_t)g,
      (__attribute__((address_space(3))) uint32_t*)(uint32_t)(uintptr_t)l,
      16, 0, 0);
}

__device__ __forceinline__ unsigned short f2bf(float f){
  unsigned u = __builtin_bit_cast(unsigned, f);
  u += 0x7fff + ((u >> 16) & 1);          // round-to-nearest-even
  return (unsigned short)(u >> 16);
}

// ---------------- fp32 -> bf16 convert ----------------
__global__ void cvt_kernel(const float* __restrict__ in, unsigned short* __restrict__ out, int n4){
  const float4*  in4  = (const float4*)in;
  ushort4*       out4 = (ushort4*)out;
  int i = blockIdx.x * blockDim.x + threadIdx.x;
  int stride = gridDim.x * blockDim.x;
  for (; i < n4; i += stride){
    float4 v = in4[i];
    ushort4 o;
    o.x = f2bf(v.x); o.y = f2bf(v.y); o.z = f2bf(v.z); o.w = f2bf(v.w);
    out4[i] = o;
  }
}

// ---------------- GEMM: C[m,n] = sum_k A[m,k]*B[n,k]  (B^T layout) ----------------
template<int EPI>
__global__ __launch_bounds__(256)
void gemm_bt(const __bf16* __restrict__ Ag, const __bf16* __restrict__ Bg,
             int M, int N, int K,
             __bf16* __restrict__ Qo, __bf16* __restrict__ Ko, __bf16* __restrict__ Vt,
             float* __restrict__ Co){
  __shared__ __align__(16) __bf16 As[128*32];
  __shared__ __align__(16) __bf16 Bs[128*32];
  const int tid  = threadIdx.x;
  const int wave = tid >> 6, lane = tid & 63;
  const int wr = wave >> 1, wc = wave & 1;
  const int lr = lane & 15, lg = lane >> 4;
  const int m0 = blockIdx.y * 128, n0 = blockIdx.x * 128;

  f32x4 acc[4][4] = {};

  const int srow = lane >> 2;        // 0..15
  const int scol = (lane & 3) * 8;   // 0,8,16,24
  const __bf16* gA = Ag + (size_t)(m0 + wave*32 + srow) * K + scol;
  const __bf16* gB = Bg + (size_t)(n0 + wave*32 + srow) * K + scol;
  __bf16* lA = &As[(wave*32) * 32];
  __bf16* lB = &Bs[(wave*32) * 32];

  for (int k0 = 0; k0 < K; k0 += 32){
    __syncthreads();
    gload_lds16(gA + k0,                lA);
    gload_lds16(gA + k0 + (size_t)16*K, lA + 16*32);
    gload_lds16(gB + k0,                lB);
    gload_lds16(gB + k0 + (size_t)16*K, lB + 16*32);
    __syncthreads();

    bf16x8 af[4], bfv[4];
#pragma unroll
    for (int i = 0; i < 4; i++)
      af[i] = *(const bf16x8*)&As[(wr*64 + i*16 + lr)*32 + lg*8];
#pragma unroll
    for (int j = 0; j < 4; j++)
      bfv[j] = *(const bf16x8*)&Bs[(wc*64 + j*16 + lr)*32 + lg*8];
#pragma unroll
    for (int i = 0; i < 4; i++)
#pragma unroll
      for (int j = 0; j < 4; j++)
        acc[i][j] = mfma16(af[i], bfv[j], acc[i][j]);
  }

  if (EPI == 0){
    const int three = n0 >> 10;
#pragma unroll
    for (int i = 0; i < 4; i++){
#pragma unroll
      for (int j = 0; j < 4; j++){
#pragma unroll
        for (int r = 0; r < 4; r++){
          int m = m0 + wr*64 + i*16 + lg*4 + r;
          int n = n0 + wc*64 + j*16 + lr;
          int b = m >> 11, s = m & 2047;
          int h = (n >> 6) & 15, dk = n & 63;
          __bf16 val = (__bf16)acc[i][j][r];
          if (three == 0)      Qo[(((size_t)(b*NHEADS + h))*SEQ + s)*DKH + dk] = val;
          else if (three == 1) Ko[(((size_t)(b*NHEADS + h))*SEQ + s)*DKH + dk] = val;
          else                 Vt[(((size_t)(b*NHEADS + h))*DKH + dk)*SEQ + s] = val;
        }
      }
    }
  } else {
#pragma unroll
    for (int i = 0; i < 4; i++)
#pragma unroll
      for (int j = 0; j < 4; j++)
#pragma unroll
        for (int r = 0; r < 4; r++){
          int m = m0 + wr*64 + i*16 + lg*4 + r;
          int n = n0 + wc*64 + j*16 + lr;
          Co[(size_t)m * N + n] = acc[i][j][r];
        }
  }
}

// ---------------- causal flash attention, LDS-staged K/V, 2-wave blocks ----------------
// Q,K: [b,h,s,dk] bf16; Vt: [b,h,dk,s] bf16; Aout: [b,s,h*64+dk] bf16
// 64 q-tiles of 32 rows; a block handles pair (j, 63-j) -> constant 33 kv-rounds.
// 1024 blocks = 4 blocks/CU (4 x 32KB LDS = 128KB): 4 independent barrier groups.
// XCD-confinement swizzle: linear id L -> xcd = L&7 (HW round-robin), and we map
// bh = xcd*4 + (L>>3)/32 so ALL 32 blocks of one bh land on ONE XCD; per-XCD
// working set = 4 bh x (Q+K+V = 768KB) = 3MB < 4MB L2 -> K/V re-reads hit L2.
// Per kv-round: K-tile [64][128B] + V-tile [64 dk][128B] staged via global_load_lds,
// XOR-swizzled (byte ^= (row&7)<<4; pre-swizzled global source + swizzled read).
__global__ __launch_bounds__(128)
void attn_kernel(const __bf16* __restrict__ Q, const __bf16* __restrict__ K,
                 const __bf16* __restrict__ Vt, __bf16* __restrict__ Aout){
  const int id   = blockIdx.x;               // 0..1023
  const int xcd  = id & 7;
  const int slot = id >> 3;                  // 0..127
  const int bh   = (xcd << 2) | (slot >> 5); // 4 bh per XCD
  const int j    = slot & 31;                // pair index 0..31
  const int wave = threadIdx.x >> 6, lane = threadIdx.x & 63;
  const int lr = lane & 15, lg = lane >> 4;
  const int swz = (lr & 7) << 4;             // read-side XOR (row&7 == lr&7 for rows t*16+lr)

  const __bf16* Qh = Q + (size_t)bh*SEQ*DKH;
  const char* Kc = (const char*)(K  + (size_t)bh*SEQ*DKH);   // row stride 128B
  const char* Vc = (const char*)(Vt + (size_t)bh*DKH*SEQ);   // row stride 4096B

  __shared__ __align__(16) char lds[2][16384];   // [buf][ K 8KB | V 8KB ]

  // staging: wave stages rows [wave*32, wave*32+32) in 4 chunks of 8 rows;
  // lane covers (row8 = lane>>3, 16B chunk (lane&7)*16); global col pre-swizzled.
  const int row8 = lane >> 3;
  const int cG   = ((lane & 7) << 4) ^ (row8 << 4);

  const int b = bh >> 4, h = bh & 15;
  const float k2 = 0.125f * 1.44269504088896340736f;   // scale * log2(e)

  for (int ph = 0; ph < 2; ph++){
    const int tb  = ph ? (63 - j) : j;       // 32-row q-tile index
    const int qw  = tb*32 + wave*16;         // wave's first q row
    const int nkv = (tb >> 1) + 1;           // kv tiles of 64 covering tile rows

    bf16x8 qf0 = *(const bf16x8*)(Qh + (size_t)(qw + lr)*DKH + lg*8);
    bf16x8 qf1 = *(const bf16x8*)(Qh + (size_t)(qw + lr)*DKH + 32 + lg*8);

    f32x4 o[4] = {};
    float mrun = -1e30f, lrun = 0.f;

    // prologue: stage tile 0 into buf 0 (4 K chunks + 4 V chunks per wave)
#pragma unroll
    for (int i = 0; i < 4; i++){
      const int srow = wave*32 + i*8 + row8;
      gload_lds16(Kc + (size_t)srow*128 + cG,  &lds[0][wave*4096 + i*1024]);
      gload_lds16(Vc + (size_t)srow*4096 + cG, &lds[0][8192 + wave*4096 + i*1024]);
    }
    __syncthreads();

    for (int kb = 0; kb < nkv; kb++){
      const int kv0 = kb*64;
      if (kb + 1 < nkv){                     // stage next tile into other buffer
        const int nv0 = kv0 + 64;
#pragma unroll
        for (int i = 0; i < 4; i++){
          const int srow = wave*32 + i*8 + row8;
          gload_lds16(Kc + (size_t)(nv0 + srow)*128 + cG,
                      &lds[(kb+1)&1][wave*4096 + i*1024]);
          gload_lds16(Vc + (size_t)srow*4096 + (size_t)nv0*2 + cG,
                      &lds[(kb+1)&1][8192 + wave*4096 + i*1024]);
        }
      }
      const char* Ks = lds[kb&1];
      const char* Vs = lds[kb&1] + 8192;

      // ---- QK^T (swapped): sf[t][r] = S[kv0+t*16+lg*4+r][qw+lr]
      f32x4 sf[4];
      __builtin_amdgcn_s_setprio(1);
#pragma unroll
      for (int t = 0; t < 4; t++){
        const int row = t*16 + lr;
        bf16x8 kf0 = *(const bf16x8*)(Ks + row*128 + ((lg*16) ^ swz));
        bf16x8 kf1 = *(const bf16x8*)(Ks + row*128 + ((64 + lg*16) ^ swz));
        f32x4 c = {};
        c = mfma16(kf0, qf0, c);
        c = mfma16(kf1, qf1, c);
        sf[t] = c;
      }
      __builtin_amdgcn_s_setprio(0);
      // ---- mask + scale
      if (kv0 + 63 > qw){                    // tile touches the diagonal
        const int q = qw + lr;
#pragma unroll
        for (int t = 0; t < 4; t++)
#pragma unroll
          for (int r = 0; r < 4; r++){
            int kv = kv0 + t*16 + lg*4 + r;
            sf[t][r] = (kv <= q) ? sf[t][r]*k2 : -1e30f;
          }
      } else {
#pragma unroll
        for (int t = 0; t < 4; t++)
#pragma unroll
          for (int r = 0; r < 4; r++)
            sf[t][r] *= k2;
      }
      // ---- row max: in-lane 16 values, then across 4 lanes sharing q-row lr
      float mx = sf[0][0];
#pragma unroll
      for (int t = 0; t < 4; t++)
#pragma unroll
        for (int r = 0; r < 4; r++) mx = fmaxf(mx, sf[t][r]);
      mx = fmaxf(mx, __shfl_xor(mx, 16));
      mx = fmaxf(mx, __shfl_xor(mx, 32));

      float mn = fmaxf(mrun, mx);
      float alpha = __builtin_amdgcn_exp2f(mrun - mn);
      mrun = mn;
      lrun *= alpha;

      // ---- P = exp2(s-m), per-lane partial row sum
      float p[16];
#pragma unroll
      for (int t = 0; t < 4; t++)
#pragma unroll
        for (int r = 0; r < 4; r++){
          float v = __builtin_amdgcn_exp2f(sf[t][r] - mn);
          p[t*4 + r] = v;
          lrun += v;
        }

      // ---- rescale O (alpha of q-row lg*4+r lives at lane lg*4+r)
      float av[4];
#pragma unroll
      for (int r = 0; r < 4; r++) av[r] = __shfl(alpha, lg*4 + r);
#pragma unroll
      for (int n = 0; n < 4; n++)
#pragma unroll
        for (int r = 0; r < 4; r++) o[n][r] *= av[r];

      // ---- PV: pa regs ARE the A-fragment under relabeled k-slots
      bf16x8 pa0, pa1;
#pragma unroll
      for (int i = 0; i < 8; i++){ pa0[i] = (__bf16)p[i]; pa1[i] = (__bf16)p[8 + i]; }
      __builtin_amdgcn_s_setprio(1);
#pragma unroll
      for (int n = 0; n < 4; n++){
        const int row = n*16 + lr;
        bf16x4 vlo0 = *(const bf16x4*)(Vs + row*128 + ((lg*8) ^ swz));
        bf16x4 vhi0 = *(const bf16x4*)(Vs + row*128 + ((32 + lg*8) ^ swz));
        bf16x4 vlo1 = *(const bf16x4*)(Vs + row*128 + ((64 + lg*8) ^ swz));
        bf16x4 vhi1 = *(const bf16x4*)(Vs + row*128 + ((96 + lg*8) ^ swz));
        bf16x8 vf0 = __builtin_shufflevector(vlo0, vhi0, 0,1,2,3,4,5,6,7);
        bf16x8 vf1 = __builtin_shufflevector(vlo1, vhi1, 0,1,2,3,4,5,6,7);
        o[n] = mfma16(pa0, vf0, o[n]);
        o[n] = mfma16(pa1, vf1, o[n]);
      }
      __builtin_amdgcn_s_setprio(0);
      __syncthreads();                       // tile consumed; next staging safe
    }

    // ---- epilogue: full row sums, direct store (wave owns its 16 q-rows)
    lrun += __shfl_xor(lrun, 16);
    lrun += __shfl_xor(lrun, 32);
    float inv = 1.0f / lrun;
#pragma unroll
    for (int r = 0; r < 4; r++){
      float invr = __shfl(inv, lg*4 + r);
      __bf16* dst = Aout + ((size_t)b*SEQ + qw + lg*4 + r)*DMODEL + h*DKH;
#pragma unroll
      for (int n = 0; n < 4; n++)
        dst[n*16 + lr] = (__bf16)(o[n][r] * invr);
    }
  }
}

// ---------------- launch ----------------
extern "C" void kernel_launch(void* const* d_in, const int* in_sizes, int n_in,
                              void* d_out, int out_size, void* d_ws, size_t ws_size,
                              hipStream_t stream){
  const float* x    = (const float*)d_in[0];
  const float* wqkv = (const float*)d_in[1];
  const float* wout = (const float*)d_in[2];
  float* out = (float*)d_out;
  char* ws = (char*)d_ws;

  __bf16* xb  = (__bf16*)(ws);                    //  8,388,608  x bf16 [4096,1024]
  __bf16* Ab  = (__bf16*)(ws);                    //  attn out bf16 (alias, x dead)
  __bf16* wqb = (__bf16*)(ws + 8388608);          //  6,291,456  W_qkv bf16
  __bf16* wob = (__bf16*)(ws + 14680064);         //  2,097,152  W_out bf16
  __bf16* Qb  = (__bf16*)(ws + 16777216);         //  8,388,608  Q [b,h,s,dk]
  __bf16* Kb  = (__bf16*)(ws + 25165824);         //  8,388,608  K [b,h,s,dk]
  __bf16* Vtb = (__bf16*)(ws + 33554432);         //  8,388,608  V^T [b,h,dk,s]

  cvt_kernel<<<1024, 256, 0, stream>>>(x,    (unsigned short*)xb,  (MTOT*DMODEL)/4);
  cvt_kernel<<<1024, 256, 0, stream>>>(wqkv, (unsigned short*)wqb, (3*DMODEL*DMODEL)/4);
  cvt_kernel<<<256,  256, 0, stream>>>(wout, (unsigned short*)wob, (DMODEL*DMODEL)/4);

  gemm_bt<0><<<dim3(24, 32), 256, 0, stream>>>(xb, wqb, MTOT, 3*DMODEL, DMODEL,
                                               Qb, Kb, Vtb, nullptr);
  attn_kernel<<<1024, 128, 0, stream>>>(Qb, Kb, Vtb, Ab);
  gemm_bt<1><<<dim3(8, 32), 256, 0, stream>>>(Ab, wob, MTOT, DMODEL, DMODEL,
                                              nullptr, nullptr, nullptr, out);
}

// Round 7
// 184.356 us; speedup vs baseline: 1.2124x; 1.1037x over previous
//
#include <hip/hip_runtime.h>
#include <stdint.h>

#define DMODEL 1024
#define NHEADS 16
#define DKH 64
#define BATCH 2
#define SEQ 2048
#define MTOT (BATCH*SEQ)   // 4096

typedef __bf16 bf16x8 __attribute__((ext_vector_type(8)));
typedef __bf16 bf16x4 __attribute__((ext_vector_type(4)));
typedef float  f32x4  __attribute__((ext_vector_type(4)));

__device__ __forceinline__ f32x4 mfma16(bf16x8 a, bf16x8 b, f32x4 c){
  return __builtin_amdgcn_mfma_f32_16x16x32_bf16(a, b, c, 0, 0, 0);
}

// async global->LDS, 16B per lane. LDS dest wave-uniform base; lane i lands at base + i*16.
__device__ __forceinline__ void gload_lds16(const void* g, void* l){
  __builtin_amdgcn_global_load_lds(
      (const __attribute__((address_space(1))) uint32_t*)(uintptr_t)g,
      (__attribute__((address_space(3))) uint32_t*)(uint32_t)(uintptr_t)l,
      16, 0, 0);
}

__device__ __forceinline__ unsigned short f2bf(float f){
  unsigned u = __builtin_bit_cast(unsigned, f);
  u += 0x7fff + ((u >> 16) & 1);          // round-to-nearest-even
  return (unsigned short)(u >> 16);
}

// scale * log2(e), folded into Q at the QKV epilogue
#define QSCALE 0.1803368801111372f        // 0.125 * 1.4426950408889634

// ---------------- fp32 -> bf16 convert ----------------
__global__ void cvt_kernel(const float* __restrict__ in, unsigned short* __restrict__ out, int n4){
  const float4*  in4  = (const float4*)in;
  ushort4*       out4 = (ushort4*)out;
  int i = blockIdx.x * blockDim.x + threadIdx.x;
  int stride = gridDim.x * blockDim.x;
  for (; i < n4; i += stride){
    float4 v = in4[i];
    ushort4 o;
    o.x = f2bf(v.x); o.y = f2bf(v.y); o.z = f2bf(v.z); o.w = f2bf(v.w);
    out4[i] = o;
  }
}

// ---------------- GEMM: C[m,n] = sum_k A[m,k]*B[n,k]  (B^T layout) ----------------
// Single-barrier double-buffered staging (T3 2-phase): per K-step
//   sync (drains prev-issued stage of current buf) -> issue STAGE(next) -> compute(cur)
// EPI==0 (BMxBN=128x128): scatter to Q (pre-scaled by QSCALE), K, Vt (bf16)
// EPI==1 (BMxBN=128x64):  fp32 store to Co
template<int EPI, int BM, int BN>
__global__ __launch_bounds__(256)
void gemm_bt(const __bf16* __restrict__ Ag, const __bf16* __restrict__ Bg,
             int M, int N, int K,
             __bf16* __restrict__ Qo, __bf16* __restrict__ Ko, __bf16* __restrict__ Vt,
             float* __restrict__ Co){
  constexpr int AM = BM/32;          // A fragments per wave (wave covers BM/2 rows)
  constexpr int AN = BN/32;          // B fragments per wave
  constexpr int CA = BM/64;          // A staging chunks (16 rows each) per wave
  constexpr int CB = BN/64;          // B staging chunks per wave
  __shared__ __align__(16) __bf16 As[2][BM*32];
  __shared__ __align__(16) __bf16 Bs[2][BN*32];
  const int tid  = threadIdx.x;
  const int wave = tid >> 6, lane = tid & 63;
  const int wr = wave >> 1, wc = wave & 1;
  const int lr = lane & 15, lg = lane >> 4;
  const int m0 = blockIdx.y * BM, n0 = blockIdx.x * BN;

  f32x4 acc[AM][AN] = {};

  const int srow = lane >> 2;        // 0..15
  const int scol = (lane & 3) * 8;   // 0,8,16,24
  const __bf16* gA = Ag + (size_t)(m0 + wave*(BM/4) + srow) * K + scol;
  const __bf16* gB = Bg + (size_t)(n0 + wave*(BN/4) + srow) * K + scol;

  const int nk = K >> 5;

  // prologue: stage k-step 0 into buf 0
#pragma unroll
  for (int c = 0; c < CA; c++)
    gload_lds16(gA + (size_t)(c*16)*K, &As[0][(wave*(BM/4) + c*16)*32]);
#pragma unroll
  for (int c = 0; c < CB; c++)
    gload_lds16(gB + (size_t)(c*16)*K, &Bs[0][(wave*(BN/4) + c*16)*32]);

  for (int t = 0; t < nk; t++){
    __syncthreads();                 // drains stage of buf[t&1] (issued last iter; hidden under compute)
    if (t + 1 < nk){                 // issue next-tile staging into other buffer
      const int k0 = (t+1) << 5, b = (t+1) & 1;
#pragma unroll
      for (int c = 0; c < CA; c++)
        gload_lds16(gA + k0 + (size_t)(c*16)*K, &As[b][(wave*(BM/4) + c*16)*32]);
#pragma unroll
      for (int c = 0; c < CB; c++)
        gload_lds16(gB + k0 + (size_t)(c*16)*K, &Bs[b][(wave*(BN/4) + c*16)*32]);
    }
    const int cb = t & 1;
    bf16x8 af[AM], bfv[AN];
#pragma unroll
    for (int i = 0; i < AM; i++)
      af[i] = *(const bf16x8*)&As[cb][(wr*(BM/2) + i*16 + lr)*32 + lg*8];
#pragma unroll
    for (int j = 0; j < AN; j++)
      bfv[j] = *(const bf16x8*)&Bs[cb][(wc*(BN/2) + j*16 + lr)*32 + lg*8];
#pragma unroll
    for (int i = 0; i < AM; i++)
#pragma unroll
      for (int j = 0; j < AN; j++)
        acc[i][j] = mfma16(af[i], bfv[j], acc[i][j]);
  }

  if (EPI == 0){
    const int three = n0 >> 10;      // block-uniform: 0=Q, 1=K, 2=V
#pragma unroll
    for (int i = 0; i < AM; i++){
#pragma unroll
      for (int j = 0; j < AN; j++){
#pragma unroll
        for (int r = 0; r < 4; r++){
          int m = m0 + wr*(BM/2) + i*16 + lg*4 + r;
          int n = n0 + wc*(BN/2) + j*16 + lr;
          int b = m >> 11, s = m & 2047;
          int h = (n >> 6) & 15, dk = n & 63;
          if (three == 0)      Qo[(((size_t)(b*NHEADS + h))*SEQ + s)*DKH + dk] = (__bf16)(acc[i][j][r] * QSCALE);
          else if (three == 1) Ko[(((size_t)(b*NHEADS + h))*SEQ + s)*DKH + dk] = (__bf16)acc[i][j][r];
          else                 Vt[(((size_t)(b*NHEADS + h))*DKH + dk)*SEQ + s] = (__bf16)acc[i][j][r];
        }
      }
    }
  } else {
#pragma unroll
    for (int i = 0; i < AM; i++)
#pragma unroll
      for (int j = 0; j < AN; j++)
#pragma unroll
        for (int r = 0; r < 4; r++){
          int m = m0 + wr*(BM/2) + i*16 + lg*4 + r;
          int n = n0 + wc*(BN/2) + j*16 + lr;
          Co[(size_t)m * N + n] = acc[i][j][r];
        }
  }
}

// ---------------- causal flash attention, LDS-staged K/V, 2-wave blocks ----------------
// Q (pre-scaled by QSCALE), K: [b,h,s,dk] bf16; Vt: [b,h,dk,s] bf16; Aout: [b,s,h*64+dk] bf16
// 64 q-tiles of 32 rows; a block handles pair (j, 63-j) -> constant 33 kv-rounds.
// 1024 blocks = 4 blocks/CU; XCD-confinement swizzle keeps all 32 blocks of one bh
// on one XCD (per-XCD working set 3MB < 4MB L2 -> K/V re-reads hit L2; FETCH 12MB, R6).
// T13 defer-rescale: skip O-rescale when __all(mx <= mrun+8); P bounded by 2^8 (bf16-safe).
__global__ __launch_bounds__(128)
void attn_kernel(const __bf16* __restrict__ Q, const __bf16* __restrict__ K,
                 const __bf16* __restrict__ Vt, __bf16* __restrict__ Aout){
  const int id   = blockIdx.x;               // 0..1023
  const int xcd  = id & 7;
  const int slot = id >> 3;                  // 0..127
  const int bh   = (xcd << 2) | (slot >> 5); // 4 bh per XCD
  const int j    = slot & 31;                // pair index 0..31
  const int wave = threadIdx.x >> 6, lane = threadIdx.x & 63;
  const int lr = lane & 15, lg = lane >> 4;
  const int swz = (lr & 7) << 4;             // read-side XOR (row&7 == lr&7 for rows t*16+lr)

  const __bf16* Qh = Q + (size_t)bh*SEQ*DKH;
  const char* Kc = (const char*)(K  + (size_t)bh*SEQ*DKH);   // row stride 128B
  const char* Vc = (const char*)(Vt + (size_t)bh*DKH*SEQ);   // row stride 4096B

  __shared__ __align__(16) char lds[2][16384];   // [buf][ K 8KB | V 8KB ]

  // staging: wave stages rows [wave*32, wave*32+32) in 4 chunks of 8 rows;
  // lane covers (row8 = lane>>3, 16B chunk (lane&7)*16); global col pre-swizzled.
  const int row8 = lane >> 3;
  const int cG   = ((lane & 7) << 4) ^ (row8 << 4);

  const int b = bh >> 4, h = bh & 15;

  for (int ph = 0; ph < 2; ph++){
    const int tb  = ph ? (63 - j) : j;       // 32-row q-tile index
    const int qw  = tb*32 + wave*16;         // wave's first q row
    const int nkv = (tb >> 1) + 1;           // kv tiles of 64 covering tile rows

    bf16x8 qf0 = *(const bf16x8*)(Qh + (size_t)(qw + lr)*DKH + lg*8);
    bf16x8 qf1 = *(const bf16x8*)(Qh + (size_t)(qw + lr)*DKH + 32 + lg*8);

    f32x4 o[4] = {};
    float mrun = -1e30f, lrun = 0.f;

    // prologue: stage tile 0 into buf 0 (4 K chunks + 4 V chunks per wave)
#pragma unroll
    for (int i = 0; i < 4; i++){
      const int srow = wave*32 + i*8 + row8;
      gload_lds16(Kc + (size_t)srow*128 + cG,  &lds[0][wave*4096 + i*1024]);
      gload_lds16(Vc + (size_t)srow*4096 + cG, &lds[0][8192 + wave*4096 + i*1024]);
    }
    __syncthreads();

    for (int kb = 0; kb < nkv; kb++){
      const int kv0 = kb*64;
      if (kb + 1 < nkv){                     // stage next tile into other buffer
        const int nv0 = kv0 + 64;
#pragma unroll
        for (int i = 0; i < 4; i++){
          const int srow = wave*32 + i*8 + row8;
          gload_lds16(Kc + (size_t)(nv0 + srow)*128 + cG,
                      &lds[(kb+1)&1][wave*4096 + i*1024]);
          gload_lds16(Vc + (size_t)srow*4096 + (size_t)nv0*2 + cG,
                      &lds[(kb+1)&1][8192 + wave*4096 + i*1024]);
        }
      }
      const char* Ks = lds[kb&1];
      const char* Vs = lds[kb&1] + 8192;

      // ---- QK^T (swapped): sf[t][r] = S[kv0+t*16+lg*4+r][qw+lr] (already exp2-domain)
      f32x4 sf[4];
      __builtin_amdgcn_s_setprio(1);
#pragma unroll
      for (int t = 0; t < 4; t++){
        const int row = t*16 + lr;
        bf16x8 kf0 = *(const bf16x8*)(Ks + row*128 + ((lg*16) ^ swz));
        bf16x8 kf1 = *(const bf16x8*)(Ks + row*128 + ((64 + lg*16) ^ swz));
        f32x4 c = {};
        c = mfma16(kf0, qf0, c);
        c = mfma16(kf1, qf1, c);
        sf[t] = c;
      }
      __builtin_amdgcn_s_setprio(0);
      // ---- causal mask (diagonal tiles only; scale already folded into Q)
      if (kv0 + 63 > qw){
        const int q = qw + lr;
#pragma unroll
        for (int t = 0; t < 4; t++)
#pragma unroll
          for (int r = 0; r < 4; r++){
            int kv = kv0 + t*16 + lg*4 + r;
            sf[t][r] = (kv <= q) ? sf[t][r] : -1e30f;
          }
      }
      // ---- row max: in-lane 16 values, then across 4 lanes sharing q-row lr
      float mx = fmaxf(fmaxf(fmaxf(sf[0][0], sf[0][1]), fmaxf(sf[0][2], sf[0][3])),
                       fmaxf(fmaxf(sf[1][0], sf[1][1]), fmaxf(sf[1][2], sf[1][3])));
      float mx2 = fmaxf(fmaxf(fmaxf(sf[2][0], sf[2][1]), fmaxf(sf[2][2], sf[2][3])),
                        fmaxf(fmaxf(sf[3][0], sf[3][1]), fmaxf(sf[3][2], sf[3][3])));
      mx = fmaxf(mx, mx2);
      mx = fmaxf(mx, __shfl_xor(mx, 16));
      mx = fmaxf(mx, __shfl_xor(mx, 32));

      // ---- T13 defer-rescale: keep old max when growth <= 8 (P <= 2^8, bf16-safe)
      if (!__all(mx <= mrun + 8.0f)){
        float mn = fmaxf(mrun, mx);
        float alpha = __builtin_amdgcn_exp2f(mrun - mn);
        mrun = mn;
        lrun *= alpha;
        float av[4];
#pragma unroll
        for (int r = 0; r < 4; r++) av[r] = __shfl(alpha, lg*4 + r);
#pragma unroll
        for (int n = 0; n < 4; n++)
#pragma unroll
          for (int r = 0; r < 4; r++) o[n][r] *= av[r];
      }

      // ---- P = exp2(s-m), per-lane partial row sum
      float p[16];
#pragma unroll
      for (int t = 0; t < 4; t++)
#pragma unroll
        for (int r = 0; r < 4; r++){
          float v = __builtin_amdgcn_exp2f(sf[t][r] - mrun);
          p[t*4 + r] = v;
          lrun += v;
        }

      // ---- PV: pa regs ARE the A-fragment under relabeled k-slots
      bf16x8 pa0, pa1;
#pragma unroll
      for (int i = 0; i < 8; i++){ pa0[i] = (__bf16)p[i]; pa1[i] = (__bf16)p[8 + i]; }
      __builtin_amdgcn_s_setprio(1);
#pragma unroll
      for (int n = 0; n < 4; n++){
        const int row = n*16 + lr;
        bf16x4 vlo0 = *(const bf16x4*)(Vs + row*128 + ((lg*8) ^ swz));
        bf16x4 vhi0 = *(const bf16x4*)(Vs + row*128 + ((32 + lg*8) ^ swz));
        bf16x4 vlo1 = *(const bf16x4*)(Vs + row*128 + ((64 + lg*8) ^ swz));
        bf16x4 vhi1 = *(const bf16x4*)(Vs + row*128 + ((96 + lg*8) ^ swz));
        bf16x8 vf0 = __builtin_shufflevector(vlo0, vhi0, 0,1,2,3,4,5,6,7);
        bf16x8 vf1 = __builtin_shufflevector(vlo1, vhi1, 0,1,2,3,4,5,6,7);
        o[n] = mfma16(pa0, vf0, o[n]);
        o[n] = mfma16(pa1, vf1, o[n]);
      }
      __builtin_amdgcn_s_setprio(0);
      __syncthreads();                       // tile consumed; next staging safe
    }

    // ---- epilogue: full row sums, direct store (wave owns its 16 q-rows)
    lrun += __shfl_xor(lrun, 16);
    lrun += __shfl_xor(lrun, 32);
    float inv = 1.0f / lrun;
#pragma unroll
    for (int r = 0; r < 4; r++){
      float invr = __shfl(inv, lg*4 + r);
      __bf16* dst = Aout + ((size_t)b*SEQ + qw + lg*4 + r)*DMODEL + h*DKH;
#pragma unroll
      for (int n = 0; n < 4; n++)
        dst[n*16 + lr] = (__bf16)(o[n][r] * invr);
    }
  }
}

// ---------------- launch ----------------
extern "C" void kernel_launch(void* const* d_in, const int* in_sizes, int n_in,
                              void* d_out, int out_size, void* d_ws, size_t ws_size,
                              hipStream_t stream){
  const float* x    = (const float*)d_in[0];
  const float* wqkv = (const float*)d_in[1];
  const float* wout = (const float*)d_in[2];
  float* out = (float*)d_out;
  char* ws = (char*)d_ws;

  __bf16* xb  = (__bf16*)(ws);                    //  8,388,608  x bf16 [4096,1024]
  __bf16* Ab  = (__bf16*)(ws);                    //  attn out bf16 (alias, x dead)
  __bf16* wqb = (__bf16*)(ws + 8388608);          //  6,291,456  W_qkv bf16
  __bf16* wob = (__bf16*)(ws + 14680064);         //  2,097,152  W_out bf16
  __bf16* Qb  = (__bf16*)(ws + 16777216);         //  8,388,608  Q [b,h,s,dk] (pre-scaled)
  __bf16* Kb  = (__bf16*)(ws + 25165824);         //  8,388,608  K [b,h,s,dk]
  __bf16* Vtb = (__bf16*)(ws + 33554432);         //  8,388,608  V^T [b,h,dk,s]

  cvt_kernel<<<1024, 256, 0, stream>>>(x,    (unsigned short*)xb,  (MTOT*DMODEL)/4);
  cvt_kernel<<<1024, 256, 0, stream>>>(wqkv, (unsigned short*)wqb, (3*DMODEL*DMODEL)/4);
  cvt_kernel<<<256,  256, 0, stream>>>(wout, (unsigned short*)wob, (DMODEL*DMODEL)/4);

  gemm_bt<0,128,128><<<dim3(24, 32), 256, 0, stream>>>(xb, wqb, MTOT, 3*DMODEL, DMODEL,
                                                       Qb, Kb, Vtb, nullptr);
  attn_kernel<<<1024, 128, 0, stream>>>(Qb, Kb, Vtb, Ab);
  gemm_bt<1,128,64><<<dim3(16, 32), 256, 0, stream>>>(Ab, wob, MTOT, DMODEL, DMODEL,
                                                      nullptr, nullptr, nullptr, out);
}

// Round 8
// 172.977 us; speedup vs baseline: 1.2922x; 1.0658x over previous
//
#include <hip/hip_runtime.h>
#include <stdint.h>

#define DMODEL 1024
#define NHEADS 16
#define DKH 64
#define BATCH 2
#define SEQ 2048
#define MTOT (BATCH*SEQ)   // 4096

typedef __bf16 bf16x8 __attribute__((ext_vector_type(8)));
typedef __bf16 bf16x4 __attribute__((ext_vector_type(4)));
typedef float  f32x4  __attribute__((ext_vector_type(4)));

__device__ __forceinline__ f32x4 mfma16(bf16x8 a, bf16x8 b, f32x4 c){
  return __builtin_amdgcn_mfma_f32_16x16x32_bf16(a, b, c, 0, 0, 0);
}

// async global->LDS, 16B per lane. LDS dest wave-uniform base; lane i lands at base + i*16.
__device__ __forceinline__ void gload_lds16(const void* g, void* l){
  __builtin_amdgcn_global_load_lds(
      (const __attribute__((address_space(1))) uint32_t*)(uintptr_t)g,
      (__attribute__((address_space(3))) uint32_t*)(uint32_t)(uintptr_t)l,
      16, 0, 0);
}

__device__ __forceinline__ unsigned short f2bf(float f){
  unsigned u = __builtin_bit_cast(unsigned, f);
  u += 0x7fff + ((u >> 16) & 1);          // round-to-nearest-even
  return (unsigned short)(u >> 16);
}

// scale * log2(e), folded into Q at the QKV epilogue
#define QSCALE 0.1803368801111372f        // 0.125 * 1.4426950408889634

// ---------------- fused fp32 -> bf16 convert (x, W_qkv, W_out in one launch) ----------------
__global__ void cvt3_kernel(const float* __restrict__ a, const float* __restrict__ b,
                            const float* __restrict__ c,
                            unsigned short* __restrict__ oa, unsigned short* __restrict__ ob,
                            unsigned short* __restrict__ oc,
                            int na4, int nb4, int nc4){
  int i = blockIdx.x * blockDim.x + threadIdx.x;
  const int tot = na4 + nb4 + nc4;
  const int stride = gridDim.x * blockDim.x;
  for (; i < tot; i += stride){
    const float4* s; ushort4* d; int k;
    if (i < na4)            { s = (const float4*)a; d = (ushort4*)oa; k = i; }
    else if (i < na4 + nb4) { s = (const float4*)b; d = (ushort4*)ob; k = i - na4; }
    else                    { s = (const float4*)c; d = (ushort4*)oc; k = i - na4 - nb4; }
    float4 v = s[k];
    ushort4 o;
    o.x = f2bf(v.x); o.y = f2bf(v.y); o.z = f2bf(v.z); o.w = f2bf(v.w);
    d[k] = o;
  }
}

// ---------------- GEMM: C[m,n] = sum_k A[m,k]*B[n,k]  (B^T layout) ----------------
// Single-barrier double-buffered staging; 1D grid with XCD-confinement swizzle
// (xcd = id&7 per measured round-robin dispatch; each XCD owns a contiguous 4-row
// m-band so A panels stay L2-resident). M is assumed 4096 (32 m-rows, 4 per XCD).
// EPI==0 (128x128): Q (pre-scaled) / K direct scatter; V via LDS-transpose ->
//                   fully coalesced Vt row stores (kills the 2B/4KB-stride scatter).
// EPI==1 (128x64):  fp32 coalesced store to Co.
template<int EPI, int BM, int BN, int NBN>
__global__ __launch_bounds__(256)
void gemm_bt(const __bf16* __restrict__ Ag, const __bf16* __restrict__ Bg,
             int M, int N, int K,
             __bf16* __restrict__ Qo, __bf16* __restrict__ Ko, __bf16* __restrict__ Vt,
             float* __restrict__ Co){
  constexpr int AM = BM/32;          // A fragments per wave
  constexpr int AN = BN/32;          // B fragments per wave
  constexpr int CA = BM/64;          // A staging chunks per wave
  constexpr int CB = BN/64;          // B staging chunks per wave
  __shared__ __align__(16) __bf16 As[2][BM*32];
  __shared__ __align__(16) __bf16 Bs[2][BN*32];
  const int tid  = threadIdx.x;
  const int wave = tid >> 6, lane = tid & 63;
  const int wr = wave >> 1, wc = wave & 1;
  const int lr = lane & 15, lg = lane >> 4;

  const int id  = blockIdx.x;
  const int xcd = id & 7;
  const int idx = id >> 3;
  const int m0  = (xcd*4 + idx/NBN) * BM;
  const int n0  = (idx % NBN) * BN;

  f32x4 acc[AM][AN] = {};

  const int srow = lane >> 2;        // 0..15
  const int scol = (lane & 3) * 8;   // 0,8,16,24
  const __bf16* gA = Ag + (size_t)(m0 + wave*(BM/4) + srow) * K + scol;
  const __bf16* gB = Bg + (size_t)(n0 + wave*(BN/4) + srow) * K + scol;

  const int nk = K >> 5;

  // prologue: stage k-step 0 into buf 0
#pragma unroll
  for (int c = 0; c < CA; c++)
    gload_lds16(gA + (size_t)(c*16)*K, &As[0][(wave*(BM/4) + c*16)*32]);
#pragma unroll
  for (int c = 0; c < CB; c++)
    gload_lds16(gB + (size_t)(c*16)*K, &Bs[0][(wave*(BN/4) + c*16)*32]);

  for (int t = 0; t < nk; t++){
    __syncthreads();                 // drains stage of buf[t&1] (hidden under prev compute)
    if (t + 1 < nk){
      const int k0 = (t+1) << 5, bb = (t+1) & 1;
#pragma unroll
      for (int c = 0; c < CA; c++)
        gload_lds16(gA + k0 + (size_t)(c*16)*K, &As[bb][(wave*(BM/4) + c*16)*32]);
#pragma unroll
      for (int c = 0; c < CB; c++)
        gload_lds16(gB + k0 + (size_t)(c*16)*K, &Bs[bb][(wave*(BN/4) + c*16)*32]);
    }
    const int cb = t & 1;
    bf16x8 af[AM], bfv[AN];
#pragma unroll
    for (int i = 0; i < AM; i++)
      af[i] = *(const bf16x8*)&As[cb][(wr*(BM/2) + i*16 + lr)*32 + lg*8];
#pragma unroll
    for (int j = 0; j < AN; j++)
      bfv[j] = *(const bf16x8*)&Bs[cb][(wc*(BN/2) + j*16 + lr)*32 + lg*8];
#pragma unroll
    for (int i = 0; i < AM; i++)
#pragma unroll
      for (int j = 0; j < AN; j++)
        acc[i][j] = mfma16(af[i], bfv[j], acc[i][j]);
  }

  if (EPI == 0){
    const int three = n0 >> 10;      // block-uniform: 0=Q, 1=K, 2=V
    if (three < 2){
#pragma unroll
      for (int i = 0; i < AM; i++){
#pragma unroll
        for (int j = 0; j < AN; j++){
#pragma unroll
          for (int r = 0; r < 4; r++){
            int m = m0 + wr*(BM/2) + i*16 + lg*4 + r;
            int n = n0 + wc*(BN/2) + j*16 + lr;
            int b = m >> 11, s = m & 2047;
            int h = (n >> 6) & 15, dk = n & 63;
            if (three == 0) Qo[(((size_t)(b*NHEADS + h))*SEQ + s)*DKH + dk] = (__bf16)(acc[i][j][r] * QSCALE);
            else            Ko[(((size_t)(b*NHEADS + h))*SEQ + s)*DKH + dk] = (__bf16)acc[i][j][r];
          }
        }
      }
    } else {
      // V: route acc through LDS, store Vt rows coalesced (32B runs).
      __bf16 (*T)[136] = (__bf16(*)[136])&As[0][0];      // [32 n][128 m] bf16, stride 136
      const int lrow = tid >> 3;          // 0..31 (LDS tile row on read side)
      const int mc   = (tid & 7) * 16;    // m-col base on read side
      const int ngr  = (n0 - 2048) + ((lrow >> 4) << 6) + (lrow & 15);  // + j*16 per chunk
      const int bb   = m0 >> 11;
      const int sbase= (m0 & 2047) + mc;
#pragma unroll
      for (int j = 0; j < AN; j++){
        __syncthreads();                  // prev chunk read done / k-loop LDS reads done
#pragma unroll
        for (int i = 0; i < AM; i++){
          bf16x4 v;
#pragma unroll
          for (int r = 0; r < 4; r++) v[r] = (__bf16)acc[i][j][r];
          *(bf16x4*)&T[wc*16 + lr][wr*64 + i*16 + lg*4] = v;
        }
        __syncthreads();
        const int ng = ngr + j*16;        // 0..1023 within V third
        __bf16* dst = Vt + (((size_t)(bb*NHEADS) + (ng >> 6))*DKH + (ng & 63))*SEQ + sbase;
        bf16x8 x0 = *(const bf16x8*)&T[lrow][mc];
        bf16x8 x1 = *(const bf16x8*)&T[lrow][mc + 8];
        *(bf16x8*)dst = x0;
        *(bf16x8*)(dst + 8) = x1;
      }
    }
  } else {
#pragma unroll
    for (int i = 0; i < AM; i++)
#pragma unroll
      for (int j = 0; j < AN; j++)
#pragma unroll
        for (int r = 0; r < 4; r++){
          int m = m0 + wr*(BM/2) + i*16 + lg*4 + r;
          int n = n0 + wc*(BN/2) + j*16 + lr;
          Co[(size_t)m * N + n] = acc[i][j][r];
        }
  }
}

// ---------------- causal flash attention (unchanged from R7: 56us, verified) ----------------
__global__ __launch_bounds__(128)
void attn_kernel(const __bf16* __restrict__ Q, const __bf16* __restrict__ K,
                 const __bf16* __restrict__ Vt, __bf16* __restrict__ Aout){
  const int id   = blockIdx.x;               // 0..1023
  const int xcd  = id & 7;
  const int slot = id >> 3;                  // 0..127
  const int bh   = (xcd << 2) | (slot >> 5); // 4 bh per XCD
  const int j    = slot & 31;                // pair index 0..31
  const int wave = threadIdx.x >> 6, lane = threadIdx.x & 63;
  const int lr = lane & 15, lg = lane >> 4;
  const int swz = (lr & 7) << 4;

  const __bf16* Qh = Q + (size_t)bh*SEQ*DKH;
  const char* Kc = (const char*)(K  + (size_t)bh*SEQ*DKH);   // row stride 128B
  const char* Vc = (const char*)(Vt + (size_t)bh*DKH*SEQ);   // row stride 4096B

  __shared__ __align__(16) char lds[2][16384];   // [buf][ K 8KB | V 8KB ]

  const int row8 = lane >> 3;
  const int cG   = ((lane & 7) << 4) ^ (row8 << 4);

  const int b = bh >> 4, h = bh & 15;

  for (int ph = 0; ph < 2; ph++){
    const int tb  = ph ? (63 - j) : j;       // 32-row q-tile index
    const int qw  = tb*32 + wave*16;         // wave's first q row
    const int nkv = (tb >> 1) + 1;

    bf16x8 qf0 = *(const bf16x8*)(Qh + (size_t)(qw + lr)*DKH + lg*8);
    bf16x8 qf1 = *(const bf16x8*)(Qh + (size_t)(qw + lr)*DKH + 32 + lg*8);

    f32x4 o[4] = {};
    float mrun = -1e30f, lrun = 0.f;

#pragma unroll
    for (int i = 0; i < 4; i++){
      const int srow = wave*32 + i*8 + row8;
      gload_lds16(Kc + (size_t)srow*128 + cG,  &lds[0][wave*4096 + i*1024]);
      gload_lds16(Vc + (size_t)srow*4096 + cG, &lds[0][8192 + wave*4096 + i*1024]);
    }
    __syncthreads();

    for (int kb = 0; kb < nkv; kb++){
      const int kv0 = kb*64;
      if (kb + 1 < nkv){
        const int nv0 = kv0 + 64;
#pragma unroll
        for (int i = 0; i < 4; i++){
          const int srow = wave*32 + i*8 + row8;
          gload_lds16(Kc + (size_t)(nv0 + srow)*128 + cG,
                      &lds[(kb+1)&1][wave*4096 + i*1024]);
          gload_lds16(Vc + (size_t)srow*4096 + (size_t)nv0*2 + cG,
                      &lds[(kb+1)&1][8192 + wave*4096 + i*1024]);
        }
      }
      const char* Ks = lds[kb&1];
      const char* Vs = lds[kb&1] + 8192;

      f32x4 sf[4];
      __builtin_amdgcn_s_setprio(1);
#pragma unroll
      for (int t = 0; t < 4; t++){
        const int row = t*16 + lr;
        bf16x8 kf0 = *(const bf16x8*)(Ks + row*128 + ((lg*16) ^ swz));
        bf16x8 kf1 = *(const bf16x8*)(Ks + row*128 + ((64 + lg*16) ^ swz));
        f32x4 c = {};
        c = mfma16(kf0, qf0, c);
        c = mfma16(kf1, qf1, c);
        sf[t] = c;
      }
      __builtin_amdgcn_s_setprio(0);
      if (kv0 + 63 > qw){
        const int q = qw + lr;
#pragma unroll
        for (int t = 0; t < 4; t++)
#pragma unroll
          for (int r = 0; r < 4; r++){
            int kv = kv0 + t*16 + lg*4 + r;
            sf[t][r] = (kv <= q) ? sf[t][r] : -1e30f;
          }
      }
      float mx = fmaxf(fmaxf(fmaxf(sf[0][0], sf[0][1]), fmaxf(sf[0][2], sf[0][3])),
                       fmaxf(fmaxf(sf[1][0], sf[1][1]), fmaxf(sf[1][2], sf[1][3])));
      float mx2 = fmaxf(fmaxf(fmaxf(sf[2][0], sf[2][1]), fmaxf(sf[2][2], sf[2][3])),
                        fmaxf(fmaxf(sf[3][0], sf[3][1]), fmaxf(sf[3][2], sf[3][3])));
      mx = fmaxf(mx, mx2);
      mx = fmaxf(mx, __shfl_xor(mx, 16));
      mx = fmaxf(mx, __shfl_xor(mx, 32));

      if (!__all(mx <= mrun + 8.0f)){
        float mn = fmaxf(mrun, mx);
        float alpha = __builtin_amdgcn_exp2f(mrun - mn);
        mrun = mn;
        lrun *= alpha;
        float av[4];
#pragma unroll
        for (int r = 0; r < 4; r++) av[r] = __shfl(alpha, lg*4 + r);
#pragma unroll
        for (int n = 0; n < 4; n++)
#pragma unroll
          for (int r = 0; r < 4; r++) o[n][r] *= av[r];
      }

      float p[16];
#pragma unroll
      for (int t = 0; t < 4; t++)
#pragma unroll
        for (int r = 0; r < 4; r++){
          float v = __builtin_amdgcn_exp2f(sf[t][r] - mrun);
          p[t*4 + r] = v;
          lrun += v;
        }

      bf16x8 pa0, pa1;
#pragma unroll
      for (int i = 0; i < 8; i++){ pa0[i] = (__bf16)p[i]; pa1[i] = (__bf16)p[8 + i]; }
      __builtin_amdgcn_s_setprio(1);
#pragma unroll
      for (int n = 0; n < 4; n++){
        const int row = n*16 + lr;
        bf16x4 vlo0 = *(const bf16x4*)(Vs + row*128 + ((lg*8) ^ swz));
        bf16x4 vhi0 = *(const bf16x4*)(Vs + row*128 + ((32 + lg*8) ^ swz));
        bf16x4 vlo1 = *(const bf16x4*)(Vs + row*128 + ((64 + lg*8) ^ swz));
        bf16x4 vhi1 = *(const bf16x4*)(Vs + row*128 + ((96 + lg*8) ^ swz));
        bf16x8 vf0 = __builtin_shufflevector(vlo0, vhi0, 0,1,2,3,4,5,6,7);
        bf16x8 vf1 = __builtin_shufflevector(vlo1, vhi1, 0,1,2,3,4,5,6,7);
        o[n] = mfma16(pa0, vf0, o[n]);
        o[n] = mfma16(pa1, vf1, o[n]);
      }
      __builtin_amdgcn_s_setprio(0);
      __syncthreads();
    }

    lrun += __shfl_xor(lrun, 16);
    lrun += __shfl_xor(lrun, 32);
    float inv = 1.0f / lrun;
#pragma unroll
    for (int r = 0; r < 4; r++){
      float invr = __shfl(inv, lg*4 + r);
      __bf16* dst = Aout + ((size_t)b*SEQ + qw + lg*4 + r)*DMODEL + h*DKH;
#pragma unroll
      for (int n = 0; n < 4; n++)
        dst[n*16 + lr] = (__bf16)(o[n][r] * invr);
    }
  }
}

// ---------------- launch ----------------
extern "C" void kernel_launch(void* const* d_in, const int* in_sizes, int n_in,
                              void* d_out, int out_size, void* d_ws, size_t ws_size,
                              hipStream_t stream){
  const float* x    = (const float*)d_in[0];
  const float* wqkv = (const float*)d_in[1];
  const float* wout = (const float*)d_in[2];
  float* out = (float*)d_out;
  char* ws = (char*)d_ws;

  __bf16* xb  = (__bf16*)(ws);                    //  8,388,608  x bf16 [4096,1024]
  __bf16* Ab  = (__bf16*)(ws);                    //  attn out bf16 (alias, x dead)
  __bf16* wqb = (__bf16*)(ws + 8388608);          //  6,291,456  W_qkv bf16
  __bf16* wob = (__bf16*)(ws + 14680064);         //  2,097,152  W_out bf16
  __bf16* Qb  = (__bf16*)(ws + 16777216);         //  8,388,608  Q [b,h,s,dk] (pre-scaled)
  __bf16* Kb  = (__bf16*)(ws + 25165824);         //  8,388,608  K [b,h,s,dk]
  __bf16* Vtb = (__bf16*)(ws + 33554432);         //  8,388,608  V^T [b,h,dk,s]

  cvt3_kernel<<<2048, 256, 0, stream>>>(x, wqkv, wout,
                                        (unsigned short*)xb, (unsigned short*)wqb, (unsigned short*)wob,
                                        (MTOT*DMODEL)/4, (3*DMODEL*DMODEL)/4, (DMODEL*DMODEL)/4);

  gemm_bt<0,128,128,24><<<768, 256, 0, stream>>>(xb, wqb, MTOT, 3*DMODEL, DMODEL,
                                                 Qb, Kb, Vtb, nullptr);
  attn_kernel<<<1024, 128, 0, stream>>>(Qb, Kb, Vtb, Ab);
  gemm_bt<1,128,64,16><<<512, 256, 0, stream>>>(Ab, wob, MTOT, DMODEL, DMODEL,
                                                nullptr, nullptr, nullptr, out);
}